// Round 17
// baseline (766.834 us; speedup 1.0000x reference)
//
#include <hip/hip_runtime.h>

#define HD   2048
#define FD   1024
#define NEXP 32
#define TOPK 6
#define TT   2048
#define SDIM 2048
#define NPAIR (TT*TOPK)
#define TSTR 76

typedef __bf16 bf16x8 __attribute__((ext_vector_type(8)));
typedef float  f32x4  __attribute__((ext_vector_type(4)));

#define GLOAD_LDS16(g, l) __builtin_amdgcn_global_load_lds( \
    (const __attribute__((address_space(1))) void*)(g),     \
    (__attribute__((address_space(3))) void*)(l), 16, 0, 0)

#define WAIT_VM3  asm volatile("s_waitcnt vmcnt(3)" ::: "memory")
#define WAIT_VM0  asm volatile("s_waitcnt vmcnt(0)" ::: "memory")
#define BAR() do { __builtin_amdgcn_s_barrier(); } while (0)

__device__ __forceinline__ ushort f2b(float f) {
  __bf16 h = (__bf16)f;
  union { __bf16 h; ushort u; } v; v.h = h;
  return v.u;
}
__device__ __forceinline__ float b2f(ushort u) {
  union { unsigned u; float f; } v; v.u = (unsigned)u << 16;
  return v.f;
}

__device__ __forceinline__ int xcd_swz(int bid, int nact) {
  int xcd = bid & 7, i = bid >> 3;
  int q = nact >> 3, r = nact & 7;
  int base = (xcd < r) ? xcd * (q + 1) : r * (q + 1) + (xcd - r) * q;
  return base + i;
}

__device__ __forceinline__ void argmax32(float &v, int &i) {
  #pragma unroll
  for (int m = 16; m >= 1; m >>= 1) {
    float ov = __shfl_xor(v, m, 32);
    int   oi = __shfl_xor(i, m, 32);
    if (ov > v || (ov == v && oi < i)) { v = ov; i = oi; }
  }
}

// per-wave gating for one token (lanes = 64)
__device__ __forceinline__ void gating_token(
    const float* __restrict__ x, const float* __restrict__ wgate, int t, int l,
    int* __restrict__ topk_idx, float* __restrict__ topk_w, int* __restrict__ cnt)
{
  int e = l & 31;
  int half = l >> 5;
  const float* xr = x + (size_t)t * HD + half * (HD/2);
  const float* wr = wgate + (size_t)e * HD + half * (HD/2);
  float acc = 0.f;
  for (int i = 0; i < HD/2; i += 4) {
    float4 a = *(const float4*)(xr + i);
    float4 b = *(const float4*)(wr + i);
    acc += a.x*b.x + a.y*b.y + a.z*b.z + a.w*b.w;
  }
  acc += __shfl_xor(acc, 32);
  float logit = acc;
  float mx = logit;
  #pragma unroll
  for (int m = 16; m >= 1; m >>= 1) mx = fmaxf(mx, __shfl_xor(mx, m, 32));
  float p = __expf(logit - mx);
  float s = p;
  #pragma unroll
  for (int m = 16; m >= 1; m >>= 1) s += __shfl_xor(s, m, 32);
  float score = p / s;
  float gs = score;
  gs = fmaxf(gs, __shfl_xor(gs, 1, 32));
  gs = fmaxf(gs, __shfl_xor(gs, 2, 32));
  int g = e >> 2;
  float gw = gs;
  bool ingroup = false;
  for (int r = 0; r < 3; ++r) {
    float v = gw; int gi = g;
    argmax32(v, gi);
    if (g == gi) { ingroup = true; gw = -1.f; }
  }
  float ms = ingroup ? score : 0.f;
  int myrank = -1;
  float denom = 1e-20f;
  float mw = ms;
  for (int r = 0; r < 6; ++r) {
    float v = mw; int ei = e;
    argmax32(v, ei);
    denom += v;
    if (e == ei) { myrank = r; mw = -1.f; }
  }
  if (l < 32 && myrank >= 0) {
    topk_idx[t*TOPK + myrank] = e;
    topk_w  [t*TOPK + myrank] = score / denom;
    atomicAdd(&cnt[e], 1);
  }
}

__global__ void scan_kernel(const int* __restrict__ cnt, int* __restrict__ offs,
                            int* __restrict__ tl_e, int* __restrict__ tl_m, int* __restrict__ ntl) {
  if (threadIdx.x == 0) {
    int o = 0, nt = 0;
    for (int e = 0; e < NEXP; ++e) {
      offs[e] = o;
      for (int m = 0; m < cnt[e]; m += 256) { tl_e[nt] = e; tl_m[nt] = m; ++nt; }
      o += cnt[e];
    }
    ntl[0] = nt;
  }
}

__global__ void fill_kernel(const int* __restrict__ topk_idx, const float* __restrict__ topk_w,
                            const int* __restrict__ offs, int* __restrict__ cur,
                            int* __restrict__ pair_tok, float* __restrict__ pair_w,
                            int* __restrict__ inv)
{
  int idx = blockIdx.x * blockDim.x + threadIdx.x;
  if (idx >= NPAIR) return;
  int e = topk_idx[idx];
  int p = offs[e] + atomicAdd(&cur[e], 1);
  pair_tok[p] = idx / TOPK;
  pair_w[p]   = topk_w[idx];
  inv[idx]    = p;
}

// one 64x64 transpose-convert tile job; t in [0,256); T = 64*TSTR ushorts of LDS
__device__ __forceinline__ void tconv_job(
    const float* __restrict__ in, ushort* __restrict__ out,
    int R, int C, int ey, int bt, int t, ushort* T)
{
  int tiles_c = C >> 6;
  int r0 = (bt / tiles_c) << 6;
  int c0 = (bt % tiles_c) << 6;
  const float* src = in + (size_t)ey * R * C;
  ushort* dst = out + (size_t)ey * R * C;
  int row = (t >> 4) << 2;
  int col4 = (t & 15) << 2;
  float vv[4][4];
  #pragma unroll
  for (int i = 0; i < 4; ++i) {
    float4 v = *(const float4*)(src + (size_t)(r0 + row + i) * C + c0 + col4);
    vv[i][0] = v.x; vv[i][1] = v.y; vv[i][2] = v.z; vv[i][3] = v.w;
  }
  #pragma unroll
  for (int cc = 0; cc < 4; ++cc)
    *(ushort4*)&T[(col4 + cc)*TSTR + row] =
      make_ushort4(f2b(vv[0][cc]), f2b(vv[1][cc]), f2b(vv[2][cc]), f2b(vv[3][cc]));
  __syncthreads();
  #pragma unroll
  for (int p = 0; p < 2; ++p) {
    int item = t + p*256;
    int oc = item >> 3, seg = item & 7;
    ushort4 a = *(const ushort4*)&T[oc*TSTR + seg*8];
    ushort4 b = *(const ushort4*)&T[oc*TSTR + seg*8 + 4];
    ushort* d = dst + (size_t)(c0 + oc) * R + r0 + seg*8;
    *(ushort4*)(d)     = a;
    *(ushort4*)(d + 4) = b;
  }
}

// ===== mega_0: [tconvA wg/wu (16384) | flat converts (8192) | gating (256)] =====
__global__ __launch_bounds__(512) void mega_0(
    const float* __restrict__ wg, const float* __restrict__ wu,
    ushort* __restrict__ wgt, ushort* __restrict__ wut,
    const float* __restrict__ x, const float* __restrict__ sg,
    const float* __restrict__ su, const float* __restrict__ sd,
    ushort* __restrict__ xb, ushort* __restrict__ sgb,
    ushort* __restrict__ sub, ushort* __restrict__ sdb,
    const float* __restrict__ wgate,
    int* __restrict__ topk_idx, float* __restrict__ topk_w, int* __restrict__ cnt)
{
  __shared__ ushort T2[2][64*TSTR];
  int b = blockIdx.x;
  int tid = threadIdx.x;
  if (b < 16384) {
    // wg+wu transpose-convert: 2 jobs/block
    int half = tid >> 8, t = tid & 255;
    int job = b * 2 + half;
    const float* in = (job < 16384) ? wg : wu;
    ushort* out = (job < 16384) ? wgt : wut;
    int j = job & 16383;
    tconv_job(in, out, HD, FD, j >> 9, j & 511, t, T2[half]);
  } else if (b < 16384 + 8192) {
    // flat fp32->bf16: 4 tensors x 2^20 float4 each; 1 float4/thread
    int g = (b - 16384) * 512 + tid;
    int sel = g >> 20;
    int i = g & 0xFFFFF;
    const float* in = (sel == 0) ? x : (sel == 1) ? sg : (sel == 2) ? su : sd;
    ushort* out = (sel == 0) ? xb : (sel == 1) ? sgb : (sel == 2) ? sub : sdb;
    float4 v = ((const float4*)in)[i];
    ((ushort4*)out)[i] = make_ushort4(f2b(v.x), f2b(v.y), f2b(v.z), f2b(v.w));
  } else {
    // gating: 8 tokens/block, one per wave
    int t = (b - (16384 + 8192)) * 8 + (tid >> 6);
    gating_token(x, wgate, t, tid & 63, topk_idx, topk_w, cnt);
  }
}

// combine: y[t] += sum_r pairout[inv[t*6+r]]
__global__ __launch_bounds__(256) void combine_kernel(
    const ushort* __restrict__ pairout, const int* __restrict__ inv, float* __restrict__ y)
{
  int t = blockIdx.x;
  int h0 = threadIdx.x * 8;
  const int* iv = inv + t*TOPK;
  float* yr = y + (size_t)t * HD + h0;
  float4 y0 = *(const float4*)(yr);
  float4 y1 = *(const float4*)(yr + 4);
  float acc[8] = {y0.x, y0.y, y0.z, y0.w, y1.x, y1.y, y1.z, y1.w};
  #pragma unroll
  for (int r = 0; r < TOPK; ++r) {
    int p = iv[r];
    const ushort* pr = pairout + (size_t)p * HD + h0;
    ushort4 a = *(const ushort4*)(pr);
    ushort4 b = *(const ushort4*)(pr + 4);
    acc[0] += b2f(a.x); acc[1] += b2f(a.y); acc[2] += b2f(a.z); acc[3] += b2f(a.w);
    acc[4] += b2f(b.x); acc[5] += b2f(b.y); acc[6] += b2f(b.z); acc[7] += b2f(b.w);
  }
  *(float4*)(yr)     = make_float4(acc[0], acc[1], acc[2], acc[3]);
  *(float4*)(yr + 4) = make_float4(acc[4], acc[5], acc[6], acc[7]);
}

// ===== mega_gu: [gu_routed (1280) | tconv(wd) (8192) | shared_gu (256)] =====
__global__ __launch_bounds__(512, 4) void mega_gu(
    const ushort* __restrict__ xb, const ushort* __restrict__ wgt, const ushort* __restrict__ wut,
    const int* __restrict__ pair_tok, const float* __restrict__ pair_w,
    const int* __restrict__ cnt, const int* __restrict__ offs,
    const int* __restrict__ tl_e, const int* __restrict__ tl_m, const int* __restrict__ ntl,
    ushort* __restrict__ act,
    const float* __restrict__ wd, ushort* __restrict__ wdt,
    const ushort* __restrict__ sgb, const ushort* __restrict__ sub, ushort* __restrict__ sact)
{
  __shared__ ushort pool[36864];   // 73728 B
  int b = blockIdx.x;
  int tid = threadIdx.x;

  if (b < 1280) {
    ushort* Ap  = pool;
    ushort* Bgp = pool + 24576;
    ushort* Bup = pool + 30720;
    int nact = ntl[0] * 16;
    if (b >= nact) return;
    int wid = xcd_swz(b, nact);
    int tile = wid >> 4;
    int nt = wid & 15;
    int e  = tl_e[tile];
    int m0 = tl_m[tile];
    int ce = cnt[e];
    int oe = offs[e];
    int n0 = nt * 64;
    int lane = tid & 63, w = tid >> 6;
    int csrc = (lane & 3) ^ ((lane >> 3) & 3);
    const ushort* asrc0; const ushort* asrc1;
    {
      int r = (2*w)*16 + (lane >> 2);
      asrc0 = xb + (size_t)pair_tok[oe + min(m0 + r,      ce - 1)] * HD + csrc * 8;
      asrc1 = xb + (size_t)pair_tok[oe + min(m0 + r + 16, ce - 1)] * HD + csrc * 8;
    }
    int tsel = w >> 2;
    int bw = w & 3;
    const ushort* bsrc = (tsel ? wut : wgt) +
        ((size_t)e * FD + n0 + bw*16 + (lane >> 2)) * HD + csrc * 8;
    ushort* bbase = (tsel ? Bup : Bgp) + bw*512;
    int lm = lane & 15, lg = lane >> 4;
    int wr = w >> 1, wc = w & 1;
    int asw = (lm >> 1) & 3;

    f32x4 accg[4][2], accu[4][2];
    #pragma unroll
    for (int m = 0; m < 4; ++m)
      #pragma unroll
      for (int n = 0; n < 2; ++n) { accg[m][n] = f32x4{0,0,0,0}; accu[m][n] = f32x4{0,0,0,0}; }

    #define GUB_ISSUE(T, BUF) do { \
      GLOAD_LDS16(asrc0 + (T)*32, Ap + (BUF)*8192 + (2*w)*512); \
      GLOAD_LDS16(asrc1 + (T)*32, Ap + (BUF)*8192 + (2*w+1)*512); \
      GLOAD_LDS16(bsrc + (T)*32, bbase + (BUF)*2048); \
    } while (0)
    #define GUB_COMPUTE(BUF) do { \
      bf16x8 a[4], bg[2], bu[2]; \
      _Pragma("unroll") \
      for (int m = 0; m < 4; ++m) \
        a[m] = *(const bf16x8*)(Ap + (BUF)*8192 + (wr*64 + m*16 + lm)*32 + (lg ^ asw)*8); \
      _Pragma("unroll") \
      for (int n = 0; n < 2; ++n) { \
        int row = wc*32 + n*16 + lm; \
        bg[n] = *(const bf16x8*)(Bgp + (BUF)*2048 + row*32 + (lg ^ asw)*8); \
        bu[n] = *(const bf16x8*)(Bup + (BUF)*2048 + row*32 + (lg ^ asw)*8); \
      } \
      __builtin_amdgcn_s_setprio(1); \
      _Pragma("unroll") \
      for (int m = 0; m < 4; ++m) \
        _Pragma("unroll") \
        for (int n = 0; n < 2; ++n) { \
          accg[m][n] = __builtin_amdgcn_mfma_f32_16x16x32_bf16(a[m], bg[n], accg[m][n], 0, 0, 0); \
          accu[m][n] = __builtin_amdgcn_mfma_f32_16x16x32_bf16(a[m], bu[n], accu[m][n], 0, 0, 0); \
        } \
      __builtin_amdgcn_s_setprio(0); \
    } while (0)

    GUB_ISSUE(0, 0);
    GUB_ISSUE(1, 1);
    WAIT_VM3;
    BAR();
    for (int tt = 0; tt < 20; ++tt) {
      int t = tt * 3;
      GUB_ISSUE(t+2, 2); GUB_COMPUTE(0); WAIT_VM3; BAR();
      GUB_ISSUE(t+3, 0); GUB_COMPUTE(1); WAIT_VM3; BAR();
      GUB_ISSUE(t+4, 1); GUB_COMPUTE(2); WAIT_VM3; BAR();
    }
    GUB_ISSUE(62, 2); GUB_COMPUTE(0); WAIT_VM3; BAR();
    GUB_ISSUE(63, 0); GUB_COMPUTE(1); WAIT_VM3; BAR();
    GUB_COMPUTE(2); WAIT_VM0; BAR();
    GUB_COMPUTE(0);
    #undef GUB_ISSUE
    #undef GUB_COMPUTE

    #pragma unroll
    for (int m = 0; m < 4; ++m) {
      #pragma unroll
      for (int j = 0; j < 4; ++j) {
        int rl = wr*64 + m*16 + lg*4 + j;
        int pi = m0 + rl;
        if (pi >= ce) continue;
        float pwv = pair_w[oe + pi];
        size_t base = (size_t)(oe + pi) * FD + n0 + wc*32;
        #pragma unroll
        for (int n = 0; n < 2; ++n) {
          float gv = accg[m][n][j];
          float uv = accu[m][n][j];
          float sv = gv / (1.f + __expf(-gv));
          act[base + n*16 + lm] = f2b(sv * uv * pwv);
        }
      }
    }
  } else if (b < 1280 + 8192) {
    ushort* T = pool + (tid >> 8) * (64*TSTR);
    int t = tid & 255;
    int job = (b - 1280) * 2 + (tid >> 8);
    tconv_job(wd, wdt, FD, HD, job >> 9, job & 511, t, T);
  } else {
    ushort* Ap  = pool;
    ushort* Bgp = pool + 24576;
    ushort* Bup = pool + 30720;
    int sbid = b - (1280 + 8192);
    int wid = (sbid & 7) * 32 + (sbid >> 3);
    int mt = wid & 7;
    int nt = wid >> 3;
    int m0 = mt * 256;
    int n0 = nt * 64;
    int lane = tid & 63, w = tid >> 6;
    int csrc = (lane & 3) ^ ((lane >> 3) & 3);
    const ushort* asrc0; const ushort* asrc1;
    {
      int r = (2*w)*16 + (lane >> 2);
      asrc0 = xb + (size_t)(m0 + r)      * HD + csrc * 8;
      asrc1 = xb + (size_t)(m0 + r + 16) * HD + csrc * 8;
    }
    int tsel = w >> 2;
    int bw = w & 3;
    const ushort* bsrc = (tsel ? sub : sgb) + (size_t)(n0 + bw*16 + (lane >> 2)) * HD + csrc * 8;
    ushort* bbase = (tsel ? Bup : Bgp) + bw*512;
    int lm = lane & 15, lg = lane >> 4;
    int wr = w >> 1, wc = w & 1;
    int asw = (lm >> 1) & 3;

    f32x4 accg[4][2], accu[4][2];
    #pragma unroll
    for (int m = 0; m < 4; ++m)
      #pragma unroll
      for (int n = 0; n < 2; ++n) { accg[m][n] = f32x4{0,0,0,0}; accu[m][n] = f32x4{0,0,0,0}; }

    #define SGB_ISSUE(T, BUF) do { \
      GLOAD_LDS16(asrc0 + (T)*32, Ap + (BUF)*8192 + (2*w)*512); \
      GLOAD_LDS16(asrc1 + (T)*32, Ap + (BUF)*8192 + (2*w+1)*512); \
      GLOAD_LDS16(bsrc + (T)*32, bbase + (BUF)*2048); \
    } while (0)
    #define SGB_COMPUTE(BUF) do { \
      bf16x8 a[4], bg[2], bu[2]; \
      _Pragma("unroll") \
      for (int m = 0; m < 4; ++m) \
        a[m] = *(const bf16x8*)(Ap + (BUF)*8192 + (wr*64 + m*16 + lm)*32 + (lg ^ asw)*8); \
      _Pragma("unroll") \
      for (int n = 0; n < 2; ++n) { \
        int row = wc*32 + n*16 + lm; \
        bg[n] = *(const bf16x8*)(Bgp + (BUF)*2048 + row*32 + (lg ^ asw)*8); \
        bu[n] = *(const bf16x8*)(Bup + (BUF)*2048 + row*32 + (lg ^ asw)*8); \
      } \
      __builtin_amdgcn_s_setprio(1); \
      _Pragma("unroll") \
      for (int m = 0; m < 4; ++m) \
        _Pragma("unroll") \
        for (int n = 0; n < 2; ++n) { \
          accg[m][n] = __builtin_amdgcn_mfma_f32_16x16x32_bf16(a[m], bg[n], accg[m][n], 0, 0, 0); \
          accu[m][n] = __builtin_amdgcn_mfma_f32_16x16x32_bf16(a[m], bu[n], accu[m][n], 0, 0, 0); \
        } \
      __builtin_amdgcn_s_setprio(0); \
    } while (0)

    SGB_ISSUE(0, 0);
    SGB_ISSUE(1, 1);
    WAIT_VM3;
    BAR();
    for (int tt = 0; tt < 20; ++tt) {
      int t = tt * 3;
      SGB_ISSUE(t+2, 2); SGB_COMPUTE(0); WAIT_VM3; BAR();
      SGB_ISSUE(t+3, 0); SGB_COMPUTE(1); WAIT_VM3; BAR();
      SGB_ISSUE(t+4, 1); SGB_COMPUTE(2); WAIT_VM3; BAR();
    }
    SGB_ISSUE(62, 2); SGB_COMPUTE(0); WAIT_VM3; BAR();
    SGB_ISSUE(63, 0); SGB_COMPUTE(1); WAIT_VM3; BAR();
    SGB_COMPUTE(2); WAIT_VM0; BAR();
    SGB_COMPUTE(0);
    #undef SGB_ISSUE
    #undef SGB_COMPUTE

    #pragma unroll
    for (int m = 0; m < 4; ++m) {
      #pragma unroll
      for (int j = 0; j < 4; ++j) {
        int rl = wr*64 + m*16 + lg*4 + j;
        size_t base = (size_t)(m0 + rl) * SDIM + n0 + wc*32;
        #pragma unroll
        for (int n = 0; n < 2; ++n) {
          float gv = accg[m][n][j];
          float uv = accu[m][n][j];
          float sv = gv / (1.f + __expf(-gv));
          sact[base + n*16 + lm] = f2b(sv * uv);
        }
      }
    }
  }
}

// ===== mega_dn: [down_routed (1280) | shared_down (128)] =====
__global__ __launch_bounds__(512, 4) void mega_dn(
    const ushort* __restrict__ act, const ushort* __restrict__ wdt,
    const int* __restrict__ cnt, const int* __restrict__ offs,
    const int* __restrict__ tl_e, const int* __restrict__ tl_m, const int* __restrict__ ntl,
    ushort* __restrict__ pairout,
    const ushort* __restrict__ sact, const ushort* __restrict__ sdb, float* __restrict__ y)
{
  __shared__ ushort pool[36864];
  int b = blockIdx.x;
  int tid = threadIdx.x;

  if (b < 1280) {
    ushort* Ap  = pool;
    ushort* Bdp = pool + 24576;
    int nact = ntl[0] * 16;
    if (b >= nact) return;
    int wid = xcd_swz(b, nact);
    int tile = wid >> 4;
    int nt = wid & 15;
    int e  = tl_e[tile];
    int m0 = tl_m[tile];
    int ce = cnt[e];
    int oe = offs[e];
    int n0 = nt * 128;
    int lane = tid & 63, w = tid >> 6;
    int csrc = (lane & 3) ^ ((lane >> 3) & 3);
    const ushort* asrc0; const ushort* asrc1;
    {
      int r = (2*w)*16 + (lane >> 2);
      asrc0 = act + (size_t)(oe + min(m0 + r,      ce - 1)) * FD + csrc * 8;
      asrc1 = act + (size_t)(oe + min(m0 + r + 16, ce - 1)) * FD + csrc * 8;
    }
    const ushort* bsrc = wdt + ((size_t)e * HD + n0 + w*16 + (lane >> 2)) * FD + csrc * 8;
    int lm = lane & 15, lg = lane >> 4;
    int wr = w >> 1, wc = w & 1;
    int asw = (lm >> 1) & 3;

    f32x4 acc[4][4];
    #pragma unroll
    for (int m = 0; m < 4; ++m)
      #pragma unroll
      for (int n = 0; n < 4; ++n) acc[m][n] = f32x4{0,0,0,0};

    #define DNB_ISSUE(T, BUF) do { \
      GLOAD_LDS16(asrc0 + (T)*32, Ap + (BUF)*8192 + (2*w)*512); \
      GLOAD_LDS16(asrc1 + (T)*32, Ap + (BUF)*8192 + (2*w+1)*512); \
      GLOAD_LDS16(bsrc + (T)*32, Bdp + (BUF)*4096 + w*512); \
    } while (0)
    #define DNB_COMPUTE(BUF) do { \
      bf16x8 a[4], bvv[4]; \
      _Pragma("unroll") \
      for (int m = 0; m < 4; ++m) \
        a[m] = *(const bf16x8*)(Ap + (BUF)*8192 + (wr*64 + m*16 + lm)*32 + (lg ^ asw)*8); \
      _Pragma("unroll") \
      for (int n = 0; n < 4; ++n) { \
        int row = wc*64 + n*16 + lm; \
        bvv[n] = *(const bf16x8*)(Bdp + (BUF)*4096 + row*32 + (lg ^ asw)*8); \
      } \
      __builtin_amdgcn_s_setprio(1); \
      _Pragma("unroll") \
      for (int m = 0; m < 4; ++m) \
        _Pragma("unroll") \
        for (int n = 0; n < 4; ++n) \
          acc[m][n] = __builtin_amdgcn_mfma_f32_16x16x32_bf16(a[m], bvv[n], acc[m][n], 0, 0, 0); \
      __builtin_amdgcn_s_setprio(0); \
    } while (0)

    DNB_ISSUE(0, 0);
    DNB_ISSUE(1, 1);
    WAIT_VM3;
    BAR();
    for (int tt = 0; tt < 10; ++tt) {
      int t = tt * 3;
      DNB_ISSUE(t+2, 2); DNB_COMPUTE(0); WAIT_VM3; BAR();
      DNB_ISSUE(t+3, 0); DNB_COMPUTE(1); WAIT_VM3; BAR();
      DNB_ISSUE(t+4, 1); DNB_COMPUTE(2); WAIT_VM3; BAR();
    }
    DNB_COMPUTE(0); WAIT_VM0; BAR();   // t=30
    DNB_COMPUTE(1);                    // t=31
    #undef DNB_ISSUE
    #undef DNB_COMPUTE

    #pragma unroll
    for (int m = 0; m < 4; ++m) {
      #pragma unroll
      for (int j = 0; j < 4; ++j) {
        int rl = wr*64 + m*16 + lg*4 + j;
        int pi = m0 + rl;
        if (pi >= ce) continue;
        size_t base = (size_t)(oe + pi) * HD + n0 + wc*64;
        #pragma unroll
        for (int n = 0; n < 4; ++n)
          pairout[base + n*16 + lm] = f2b(acc[m][n][j]);
      }
    }
  } else {
    ushort* Ap  = pool;
    ushort* Bdp = pool + 24576;
    int sbid = b - 1280;
    int wid = (sbid & 7) * 16 + (sbid >> 3);
    int mt = wid & 7;
    int nt = wid >> 3;
    int m0 = mt * 256;
    int n0 = nt * 128;
    int lane = tid & 63, w = tid >> 6;
    int csrc = (lane & 3) ^ ((lane >> 3) & 3);
    const ushort* asrc0; const ushort* asrc1;
    {
      int r = (2*w)*16 + (lane >> 2);
      asrc0 = sact + (size_t)(m0 + r)      * SDIM + csrc * 8;
      asrc1 = sact + (size_t)(m0 + r + 16) * SDIM + csrc * 8;
    }
    const ushort* bsrc = sdb + (size_t)(n0 + w*16 + (lane >> 2)) * SDIM + csrc * 8;
    int lm = lane & 15, lg = lane >> 4;
    int wr = w >> 1, wc = w & 1;
    int asw = (lm >> 1) & 3;

    f32x4 acc[4][4];
    #pragma unroll
    for (int m = 0; m < 4; ++m)
      #pragma unroll
      for (int n = 0; n < 4; ++n) acc[m][n] = f32x4{0,0,0,0};

    #define SDB_ISSUE(T, BUF) do { \
      GLOAD_LDS16(asrc0 + (T)*32, Ap + (BUF)*8192 + (2*w)*512); \
      GLOAD_LDS16(asrc1 + (T)*32, Ap + (BUF)*8192 + (2*w+1)*512); \
      GLOAD_LDS16(bsrc + (T)*32, Bdp + (BUF)*4096 + w*512); \
    } while (0)
    #define SDB_COMPUTE(BUF) do { \
      bf16x8 a[4], bvv[4]; \
      _Pragma("unroll") \
      for (int m = 0; m < 4; ++m) \
        a[m] = *(const bf16x8*)(Ap + (BUF)*8192 + (wr*64 + m*16 + lm)*32 + (lg ^ asw)*8); \
      _Pragma("unroll") \
      for (int n = 0; n < 4; ++n) { \
        int row = wc*64 + n*16 + lm; \
        bvv[n] = *(const bf16x8*)(Bdp + (BUF)*4096 + row*32 + (lg ^ asw)*8); \
      } \
      __builtin_amdgcn_s_setprio(1); \
      _Pragma("unroll") \
      for (int m = 0; m < 4; ++m) \
        _Pragma("unroll") \
        for (int n = 0; n < 4; ++n) \
          acc[m][n] = __builtin_amdgcn_mfma_f32_16x16x32_bf16(a[m], bvv[n], acc[m][n], 0, 0, 0); \
      __builtin_amdgcn_s_setprio(0); \
    } while (0)

    SDB_ISSUE(0, 0);
    SDB_ISSUE(1, 1);
    WAIT_VM3;
    BAR();
    for (int tt = 0; tt < 20; ++tt) {
      int t = tt * 3;
      SDB_ISSUE(t+2, 2); SDB_COMPUTE(0); WAIT_VM3; BAR();
      SDB_ISSUE(t+3, 0); SDB_COMPUTE(1); WAIT_VM3; BAR();
      SDB_ISSUE(t+4, 1); SDB_COMPUTE(2); WAIT_VM3; BAR();
    }
    SDB_ISSUE(62, 2); SDB_COMPUTE(0); WAIT_VM3; BAR();
    SDB_ISSUE(63, 0); SDB_COMPUTE(1); WAIT_VM3; BAR();
    SDB_COMPUTE(2); WAIT_VM0; BAR();
    SDB_COMPUTE(0);
    #undef SDB_ISSUE
    #undef SDB_COMPUTE

    #pragma unroll
    for (int m = 0; m < 4; ++m) {
      #pragma unroll
      for (int j = 0; j < 4; ++j) {
        int rl = wr*64 + m*16 + lg*4 + j;
        size_t base = (size_t)(m0 + rl) * HD + n0 + wc*64;
        #pragma unroll
        for (int n = 0; n < 4; ++n)
          y[base + n*16 + lm] = acc[m][n][j];
      }
    }
  }
}

// ---------------- launch ----------------
extern "C" void kernel_launch(void* const* d_in, const int* in_sizes, int n_in,
                              void* d_out, int out_size, void* d_ws, size_t ws_size,
                              hipStream_t stream) {
  const float* x     = (const float*)d_in[0];
  const float* wgate = (const float*)d_in[1];
  const float* wg    = (const float*)d_in[2];
  const float* wu    = (const float*)d_in[3];
  const float* wd    = (const float*)d_in[4];
  const float* sg    = (const float*)d_in[5];
  const float* su    = (const float*)d_in[6];
  const float* sd    = (const float*)d_in[7];
  float* y = (float*)d_out;
  char* ws = (char*)d_ws;

  ushort* xb   = (ushort*)(ws + 0);
  ushort* act  = (ushort*)(ws + 8388608);
  ushort* sact = (ushort*)(ws + 33554432);
  int*    tidx = (int*)  (ws + 41943040);
  float*  tw   = (float*)(ws + 41992192);
  int*    ptok = (int*)  (ws + 42041344);
  float*  pw   = (float*)(ws + 42090496);
  int*    cnt  = (int*)  (ws + 42139648);
  int*    curc = (int*)  (ws + 42139776);
  int*    offs = (int*)  (ws + 42139904);
  int*    tl_e = (int*)  (ws + 42140160);
  int*    tl_m = (int*)  (ws + 42140672);
  int*    ntl  = (int*)  (ws + 42141184);
  int*    inv  = (int*)  (ws + 42141440);
  ushort* wgt  = (ushort*)(ws + 50331648);    // 128 MB [E][F][H]
  ushort* wut  = (ushort*)(ws + 184549376);   // 128 MB
  ushort* wdt  = (ushort*)(ws + 318767104);   // 128 MB [E][H][F]
  ushort* sgb  = (ushort*)(ws + 452984832);   // 8 MB
  ushort* sub  = (ushort*)(ws + 461373440);
  ushort* sdb  = (ushort*)(ws + 469762048);
  ushort* pairout = wgt;   // aliases wgt (last read in mega_gu; written in mega_dn)

  hipMemsetAsync(cnt, 0, 512, stream);

  mega_0<<<dim3(16384 + 8192 + 256), dim3(512), 0, stream>>>(
      wg, wu, wgt, wut, x, sg, su, sd, xb, sgb, sub, sdb,
      wgate, tidx, tw, cnt);
  scan_kernel<<<dim3(1), dim3(64), 0, stream>>>(cnt, offs, tl_e, tl_m, ntl);
  fill_kernel<<<dim3(48), dim3(256), 0, stream>>>(tidx, tw, offs, curc, ptok, pw, inv);

  mega_gu<<<dim3(1280 + 8192 + 256), dim3(512), 0, stream>>>(
      xb, wgt, wut, ptok, pw, cnt, offs, tl_e, tl_m, ntl, act,
      wd, wdt, sgb, sub, sact);
  mega_dn<<<dim3(1280 + 128), dim3(512), 0, stream>>>(
      act, wdt, cnt, offs, tl_e, tl_m, ntl, pairout, sact, sdb, y);
  combine_kernel<<<dim3(TT), dim3(256), 0, stream>>>(pairout, inv, y);
}

// Round 18
// 654.958 us; speedup vs baseline: 1.1708x; 1.1708x over previous
//
#include <hip/hip_runtime.h>

#define HD   2048
#define FD   1024
#define NEXP 32
#define TOPK 6
#define TT   2048
#define SDIM 2048
#define NPAIR (TT*TOPK)
#define TSTR 76

typedef __bf16 bf16x8 __attribute__((ext_vector_type(8)));
typedef float  f32x4  __attribute__((ext_vector_type(4)));

#define GLOAD_LDS16(g, l) __builtin_amdgcn_global_load_lds( \
    (const __attribute__((address_space(1))) void*)(g),     \
    (__attribute__((address_space(3))) void*)(l), 16, 0, 0)

#define WAIT_VM3  asm volatile("s_waitcnt vmcnt(3)" ::: "memory")
#define WAIT_VM0  asm volatile("s_waitcnt vmcnt(0)" ::: "memory")
#define BAR() do { __builtin_amdgcn_s_barrier(); } while (0)

__device__ __forceinline__ ushort f2b(float f) {
  __bf16 h = (__bf16)f;
  union { __bf16 h; ushort u; } v; v.h = h;
  return v.u;
}
__device__ __forceinline__ float b2f(ushort u) {
  union { unsigned u; float f; } v; v.u = (unsigned)u << 16;
  return v.f;
}

__device__ __forceinline__ int xcd_swz(int bid, int nact) {
  int xcd = bid & 7, i = bid >> 3;
  int q = nact >> 3, r = nact & 7;
  int base = (xcd < r) ? xcd * (q + 1) : r * (q + 1) + (xcd - r) * q;
  return base + i;
}

// ---------------- gating (fp32 exact) ----------------
__device__ __forceinline__ void argmax32(float &v, int &i) {
  #pragma unroll
  for (int m = 16; m >= 1; m >>= 1) {
    float ov = __shfl_xor(v, m, 32);
    int   oi = __shfl_xor(i, m, 32);
    if (ov > v || (ov == v && oi < i)) { v = ov; i = oi; }
  }
}

__global__ __launch_bounds__(64) void gating_kernel(
    const float* __restrict__ x, const float* __restrict__ wgate,
    int* __restrict__ topk_idx, float* __restrict__ topk_w, int* __restrict__ cnt)
{
  int t = blockIdx.x;
  int l = threadIdx.x;
  int e = l & 31;
  int half = l >> 5;
  const float* xr = x + (size_t)t * HD + half * (HD/2);
  const float* wr = wgate + (size_t)e * HD + half * (HD/2);
  float acc = 0.f;
  for (int i = 0; i < HD/2; i += 4) {
    float4 a = *(const float4*)(xr + i);
    float4 b = *(const float4*)(wr + i);
    acc += a.x*b.x + a.y*b.y + a.z*b.z + a.w*b.w;
  }
  acc += __shfl_xor(acc, 32);
  float logit = acc;
  float mx = logit;
  #pragma unroll
  for (int m = 16; m >= 1; m >>= 1) mx = fmaxf(mx, __shfl_xor(mx, m, 32));
  float p = __expf(logit - mx);
  float s = p;
  #pragma unroll
  for (int m = 16; m >= 1; m >>= 1) s += __shfl_xor(s, m, 32);
  float score = p / s;
  float gs = score;
  gs = fmaxf(gs, __shfl_xor(gs, 1, 32));
  gs = fmaxf(gs, __shfl_xor(gs, 2, 32));
  int g = e >> 2;
  float gw = gs;
  bool ingroup = false;
  for (int r = 0; r < 3; ++r) {
    float v = gw; int gi = g;
    argmax32(v, gi);
    if (g == gi) { ingroup = true; gw = -1.f; }
  }
  float ms = ingroup ? score : 0.f;
  int myrank = -1;
  float denom = 1e-20f;
  float mw = ms;
  for (int r = 0; r < 6; ++r) {
    float v = mw; int ei = e;
    argmax32(v, ei);
    denom += v;
    if (e == ei) { myrank = r; mw = -1.f; }
  }
  if (l < 32 && myrank >= 0) {
    topk_idx[t*TOPK + myrank] = e;
    topk_w  [t*TOPK + myrank] = score / denom;
    atomicAdd(&cnt[e], 1);
  }
}

__global__ void scan_kernel(const int* __restrict__ cnt, int* __restrict__ offs,
                            int* __restrict__ tl_e, int* __restrict__ tl_m, int* __restrict__ ntl) {
  if (threadIdx.x == 0) {
    int o = 0, nt = 0;
    for (int e = 0; e < NEXP; ++e) {
      offs[e] = o;
      for (int m = 0; m < cnt[e]; m += 256) { tl_e[nt] = e; tl_m[nt] = m; ++nt; }
      o += cnt[e];
    }
    ntl[0] = nt;
  }
}

__global__ void fill_kernel(const int* __restrict__ topk_idx, const float* __restrict__ topk_w,
                            const int* __restrict__ offs, int* __restrict__ cur,
                            int* __restrict__ pair_tok, float* __restrict__ pair_w,
                            int* __restrict__ inv)
{
  int idx = blockIdx.x * blockDim.x + threadIdx.x;
  if (idx >= NPAIR) return;
  int e = topk_idx[idx];
  int p = offs[e] + atomicAdd(&cur[e], 1);
  pair_tok[p] = idx / TOPK;
  pair_w[p]   = topk_w[idx];
  inv[idx]    = p;
}

__global__ __launch_bounds__(256) void fconv4(
    const float* __restrict__ s0, const float* __restrict__ s1,
    const float* __restrict__ s2, const float* __restrict__ s3,
    ushort* __restrict__ d0, ushort* __restrict__ d1,
    ushort* __restrict__ d2, ushort* __restrict__ d3)
{
  int sel = blockIdx.y;
  const float* in = (sel == 0) ? s0 : (sel == 1) ? s1 : (sel == 2) ? s2 : s3;
  ushort* out = (sel == 0) ? d0 : (sel == 1) ? d1 : (sel == 2) ? d2 : d3;
  int i = blockIdx.x * blockDim.x + threadIdx.x;
  float4 v = ((const float4*)in)[i];
  ((ushort4*)out)[i] = make_ushort4(f2b(v.x), f2b(v.y), f2b(v.z), f2b(v.w));
}

// one 64x64 transpose-convert tile job; t in [0,256); T = 64*TSTR ushorts of LDS
__device__ __forceinline__ void tconv_job(
    const float* __restrict__ in, ushort* __restrict__ out,
    int R, int C, int ey, int bt, int t, ushort* T)
{
  int tiles_c = C >> 6;
  int r0 = (bt / tiles_c) << 6;
  int c0 = (bt % tiles_c) << 6;
  const float* src = in + (size_t)ey * R * C;
  ushort* dst = out + (size_t)ey * R * C;
  int row = (t >> 4) << 2;
  int col4 = (t & 15) << 2;
  float vv[4][4];
  #pragma unroll
  for (int i = 0; i < 4; ++i) {
    float4 v = *(const float4*)(src + (size_t)(r0 + row + i) * C + c0 + col4);
    vv[i][0] = v.x; vv[i][1] = v.y; vv[i][2] = v.z; vv[i][3] = v.w;
  }
  #pragma unroll
  for (int cc = 0; cc < 4; ++cc)
    *(ushort4*)&T[(col4 + cc)*TSTR + row] =
      make_ushort4(f2b(vv[0][cc]), f2b(vv[1][cc]), f2b(vv[2][cc]), f2b(vv[3][cc]));
  __syncthreads();
  #pragma unroll
  for (int p = 0; p < 2; ++p) {
    int item = t + p*256;
    int oc = item >> 3, seg = item & 7;
    ushort4 a = *(const ushort4*)&T[oc*TSTR + seg*8];
    ushort4 b = *(const ushort4*)&T[oc*TSTR + seg*8 + 4];
    ushort* d = dst + (size_t)(c0 + oc) * R + r0 + seg*8;
    *(ushort4*)(d)     = a;
    *(ushort4*)(d + 4) = b;
  }
}

// wg+wu transpose-convert: 512 thr, 2 jobs/block. jobs: 0..16383 wg, 16384..32767 wu
__global__ __launch_bounds__(512) void tconvA(
    const float* __restrict__ wg, const float* __restrict__ wu,
    ushort* __restrict__ wgt, ushort* __restrict__ wut)
{
  __shared__ ushort T2[2][64*TSTR];
  int half = threadIdx.x >> 8, t = threadIdx.x & 255;
  int job = blockIdx.x * 2 + half;
  const float* in = (job < 16384) ? wg : wu;
  ushort* out = (job < 16384) ? wgt : wut;
  int j = job & 16383;
  tconv_job(in, out, HD, FD, j >> 9, j & 511, t, T2[half]);
}

// combine: y[t] += sum_r pairout[inv[t*6+r]]
__global__ __launch_bounds__(256) void combine_kernel(
    const ushort* __restrict__ pairout, const int* __restrict__ inv, float* __restrict__ y)
{
  int t = blockIdx.x;
  int h0 = threadIdx.x * 8;
  const int* iv = inv + t*TOPK;
  float* yr = y + (size_t)t * HD + h0;
  float4 y0 = *(const float4*)(yr);
  float4 y1 = *(const float4*)(yr + 4);
  float acc[8] = {y0.x, y0.y, y0.z, y0.w, y1.x, y1.y, y1.z, y1.w};
  #pragma unroll
  for (int r = 0; r < TOPK; ++r) {
    int p = iv[r];
    const ushort* pr = pairout + (size_t)p * HD + h0;
    ushort4 a = *(const ushort4*)(pr);
    ushort4 b = *(const ushort4*)(pr + 4);
    acc[0] += b2f(a.x); acc[1] += b2f(a.y); acc[2] += b2f(a.z); acc[3] += b2f(a.w);
    acc[4] += b2f(b.x); acc[5] += b2f(b.y); acc[6] += b2f(b.z); acc[7] += b2f(b.w);
  }
  *(float4*)(yr)     = make_float4(acc[0], acc[1], acc[2], acc[3]);
  *(float4*)(yr + 4) = make_float4(acc[4], acc[5], acc[6], acc[7]);
}

// ===== mega_gu: [gu_routed (1280) | tconv(wd) (8192) | shared_gu (256)] =====
__global__ __launch_bounds__(512, 4) void mega_gu(
    const ushort* __restrict__ xb, const ushort* __restrict__ wgt, const ushort* __restrict__ wut,
    const int* __restrict__ pair_tok, const float* __restrict__ pair_w,
    const int* __restrict__ cnt, const int* __restrict__ offs,
    const int* __restrict__ tl_e, const int* __restrict__ tl_m, const int* __restrict__ ntl,
    ushort* __restrict__ act,
    const float* __restrict__ wd, ushort* __restrict__ wdt,
    const ushort* __restrict__ sgb, const ushort* __restrict__ sub, ushort* __restrict__ sact)
{
  __shared__ ushort pool[36864];   // 73728 B
  int b = blockIdx.x;
  int tid = threadIdx.x;

  if (b < 1280) {
    // ---------- gu_routed: BM=256 BN=64(x2) BK=32, 3-buf, vmcnt(3) ----------
    ushort* Ap  = pool;              // 3 x 8192
    ushort* Bgp = pool + 24576;      // 3 x 2048
    ushort* Bup = pool + 30720;      // 3 x 2048
    int nact = ntl[0] * 16;
    if (b >= nact) return;
    int wid = xcd_swz(b, nact);
    int tile = wid >> 4;
    int nt = wid & 15;
    int e  = tl_e[tile];
    int m0 = tl_m[tile];
    int ce = cnt[e];
    int oe = offs[e];
    int n0 = nt * 64;
    int lane = tid & 63, w = tid >> 6;
    int csrc = (lane & 3) ^ ((lane >> 3) & 3);
    const ushort* asrc0; const ushort* asrc1;
    {
      int r = (2*w)*16 + (lane >> 2);
      asrc0 = xb + (size_t)pair_tok[oe + min(m0 + r,      ce - 1)] * HD + csrc * 8;
      asrc1 = xb + (size_t)pair_tok[oe + min(m0 + r + 16, ce - 1)] * HD + csrc * 8;
    }
    int tsel = w >> 2;
    int bw = w & 3;
    const ushort* bsrc = (tsel ? wut : wgt) +
        ((size_t)e * FD + n0 + bw*16 + (lane >> 2)) * HD + csrc * 8;
    ushort* bbase = (tsel ? Bup : Bgp) + bw*512;
    int lm = lane & 15, lg = lane >> 4;
    int wr = w >> 1, wc = w & 1;
    int asw = (lm >> 1) & 3;

    f32x4 accg[4][2], accu[4][2];
    #pragma unroll
    for (int m = 0; m < 4; ++m)
      #pragma unroll
      for (int n = 0; n < 2; ++n) { accg[m][n] = f32x4{0,0,0,0}; accu[m][n] = f32x4{0,0,0,0}; }

    #define GUB_ISSUE(T, BUF) do { \
      GLOAD_LDS16(asrc0 + (T)*32, Ap + (BUF)*8192 + (2*w)*512); \
      GLOAD_LDS16(asrc1 + (T)*32, Ap + (BUF)*8192 + (2*w+1)*512); \
      GLOAD_LDS16(bsrc + (T)*32, bbase + (BUF)*2048); \
    } while (0)
    #define GUB_COMPUTE(BUF) do { \
      bf16x8 a[4], bg[2], bu[2]; \
      _Pragma("unroll") \
      for (int m = 0; m < 4; ++m) \
        a[m] = *(const bf16x8*)(Ap + (BUF)*8192 + (wr*64 + m*16 + lm)*32 + (lg ^ asw)*8); \
      _Pragma("unroll") \
      for (int n = 0; n < 2; ++n) { \
        int row = wc*32 + n*16 + lm; \
        bg[n] = *(const bf16x8*)(Bgp + (BUF)*2048 + row*32 + (lg ^ asw)*8); \
        bu[n] = *(const bf16x8*)(Bup + (BUF)*2048 + row*32 + (lg ^ asw)*8); \
      } \
      __builtin_amdgcn_s_setprio(1); \
      _Pragma("unroll") \
      for (int m = 0; m < 4; ++m) \
        _Pragma("unroll") \
        for (int n = 0; n < 2; ++n) { \
          accg[m][n] = __builtin_amdgcn_mfma_f32_16x16x32_bf16(a[m], bg[n], accg[m][n], 0, 0, 0); \
          accu[m][n] = __builtin_amdgcn_mfma_f32_16x16x32_bf16(a[m], bu[n], accu[m][n], 0, 0, 0); \
        } \
      __builtin_amdgcn_s_setprio(0); \
    } while (0)

    GUB_ISSUE(0, 0);
    GUB_ISSUE(1, 1);
    WAIT_VM3;
    BAR();
    for (int tt = 0; tt < 20; ++tt) {
      int t = tt * 3;
      GUB_ISSUE(t+2, 2); GUB_COMPUTE(0); WAIT_VM3; BAR();
      GUB_ISSUE(t+3, 0); GUB_COMPUTE(1); WAIT_VM3; BAR();
      GUB_ISSUE(t+4, 1); GUB_COMPUTE(2); WAIT_VM3; BAR();
    }
    GUB_ISSUE(62, 2); GUB_COMPUTE(0); WAIT_VM3; BAR();   // t=60
    GUB_ISSUE(63, 0); GUB_COMPUTE(1); WAIT_VM3; BAR();   // t=61
    GUB_COMPUTE(2); WAIT_VM0; BAR();                     // t=62
    GUB_COMPUTE(0);                                      // t=63
    #undef GUB_ISSUE
    #undef GUB_COMPUTE

    #pragma unroll
    for (int m = 0; m < 4; ++m) {
      #pragma unroll
      for (int j = 0; j < 4; ++j) {
        int rl = wr*64 + m*16 + lg*4 + j;
        int pi = m0 + rl;
        if (pi >= ce) continue;
        float pwv = pair_w[oe + pi];
        size_t base = (size_t)(oe + pi) * FD + n0 + wc*32;
        #pragma unroll
        for (int n = 0; n < 2; ++n) {
          float gv = accg[m][n][j];
          float uv = accu[m][n][j];
          float sv = gv / (1.f + __expf(-gv));
          act[base + n*16 + lm] = f2b(sv * uv * pwv);
        }
      }
    }
  } else if (b < 1280 + 8192) {
    // ---------- tconv of wd: [E][F][H] fp32 -> [E][H][F] bf16 ----------
    ushort* T = pool + (tid >> 8) * (64*TSTR);
    int t = tid & 255;
    int job = (b - 1280) * 2 + (tid >> 8);   // 16384 jobs, 512/expert
    tconv_job(wd, wdt, FD, HD, job >> 9, job & 511, t, T);
  } else {
    // ---------- shared_gu: BM=256 BN=64(x2), direct rows ----------
    ushort* Ap  = pool;
    ushort* Bgp = pool + 24576;
    ushort* Bup = pool + 30720;
    int sbid = b - (1280 + 8192);            // 0..255
    int wid = (sbid & 7) * 32 + (sbid >> 3);
    int mt = wid & 7;
    int nt = wid >> 3;                        // 0..31
    int m0 = mt * 256;
    int n0 = nt * 64;
    int lane = tid & 63, w = tid >> 6;
    int csrc = (lane & 3) ^ ((lane >> 3) & 3);
    const ushort* asrc0; const ushort* asrc1;
    {
      int r = (2*w)*16 + (lane >> 2);
      asrc0 = xb + (size_t)(m0 + r)      * HD + csrc * 8;
      asrc1 = xb + (size_t)(m0 + r + 16) * HD + csrc * 8;
    }
    int tsel = w >> 2;
    int bw = w & 3;
    const ushort* bsrc = (tsel ? sub : sgb) + (size_t)(n0 + bw*16 + (lane >> 2)) * HD + csrc * 8;
    ushort* bbase = (tsel ? Bup : Bgp) + bw*512;
    int lm = lane & 15, lg = lane >> 4;
    int wr = w >> 1, wc = w & 1;
    int asw = (lm >> 1) & 3;

    f32x4 accg[4][2], accu[4][2];
    #pragma unroll
    for (int m = 0; m < 4; ++m)
      #pragma unroll
      for (int n = 0; n < 2; ++n) { accg[m][n] = f32x4{0,0,0,0}; accu[m][n] = f32x4{0,0,0,0}; }

    #define SGB_ISSUE(T, BUF) do { \
      GLOAD_LDS16(asrc0 + (T)*32, Ap + (BUF)*8192 + (2*w)*512); \
      GLOAD_LDS16(asrc1 + (T)*32, Ap + (BUF)*8192 + (2*w+1)*512); \
      GLOAD_LDS16(bsrc + (T)*32, bbase + (BUF)*2048); \
    } while (0)
    #define SGB_COMPUTE(BUF) do { \
      bf16x8 a[4], bg[2], bu[2]; \
      _Pragma("unroll") \
      for (int m = 0; m < 4; ++m) \
        a[m] = *(const bf16x8*)(Ap + (BUF)*8192 + (wr*64 + m*16 + lm)*32 + (lg ^ asw)*8); \
      _Pragma("unroll") \
      for (int n = 0; n < 2; ++n) { \
        int row = wc*32 + n*16 + lm; \
        bg[n] = *(const bf16x8*)(Bgp + (BUF)*2048 + row*32 + (lg ^ asw)*8); \
        bu[n] = *(const bf16x8*)(Bup + (BUF)*2048 + row*32 + (lg ^ asw)*8); \
      } \
      __builtin_amdgcn_s_setprio(1); \
      _Pragma("unroll") \
      for (int m = 0; m < 4; ++m) \
        _Pragma("unroll") \
        for (int n = 0; n < 2; ++n) { \
          accg[m][n] = __builtin_amdgcn_mfma_f32_16x16x32_bf16(a[m], bg[n], accg[m][n], 0, 0, 0); \
          accu[m][n] = __builtin_amdgcn_mfma_f32_16x16x32_bf16(a[m], bu[n], accu[m][n], 0, 0, 0); \
        } \
      __builtin_amdgcn_s_setprio(0); \
    } while (0)

    SGB_ISSUE(0, 0);
    SGB_ISSUE(1, 1);
    WAIT_VM3;
    BAR();
    for (int tt = 0; tt < 20; ++tt) {
      int t = tt * 3;
      SGB_ISSUE(t+2, 2); SGB_COMPUTE(0); WAIT_VM3; BAR();
      SGB_ISSUE(t+3, 0); SGB_COMPUTE(1); WAIT_VM3; BAR();
      SGB_ISSUE(t+4, 1); SGB_COMPUTE(2); WAIT_VM3; BAR();
    }
    SGB_ISSUE(62, 2); SGB_COMPUTE(0); WAIT_VM3; BAR();   // t=60
    SGB_ISSUE(63, 0); SGB_COMPUTE(1); WAIT_VM3; BAR();   // t=61
    SGB_COMPUTE(2); WAIT_VM0; BAR();                     // t=62
    SGB_COMPUTE(0);                                      // t=63
    #undef SGB_ISSUE
    #undef SGB_COMPUTE

    #pragma unroll
    for (int m = 0; m < 4; ++m) {
      #pragma unroll
      for (int j = 0; j < 4; ++j) {
        int rl = wr*64 + m*16 + lg*4 + j;
        size_t base = (size_t)(m0 + rl) * SDIM + n0 + wc*32;
        #pragma unroll
        for (int n = 0; n < 2; ++n) {
          float gv = accg[m][n][j];
          float uv = accu[m][n][j];
          float sv = gv / (1.f + __expf(-gv));
          sact[base + n*16 + lm] = f2b(sv * uv);
        }
      }
    }
  }
}

// ===== mega_dn: [down_routed (1280) | shared_down (128)] =====
__global__ __launch_bounds__(512, 4) void mega_dn(
    const ushort* __restrict__ act, const ushort* __restrict__ wdt,
    const int* __restrict__ cnt, const int* __restrict__ offs,
    const int* __restrict__ tl_e, const int* __restrict__ tl_m, const int* __restrict__ ntl,
    ushort* __restrict__ pairout,
    const ushort* __restrict__ sact, const ushort* __restrict__ sdb, float* __restrict__ y)
{
  __shared__ ushort pool[36864];
  int b = blockIdx.x;
  int tid = threadIdx.x;

  if (b < 1280) {
    // ---------- down_routed: BM=256 BN=128 BK=32, stores bf16 pair rows ----------
    ushort* Ap  = pool;              // 3 x 8192
    ushort* Bdp = pool + 24576;      // 3 x 4096
    int nact = ntl[0] * 16;
    if (b >= nact) return;
    int wid = xcd_swz(b, nact);
    int tile = wid >> 4;
    int nt = wid & 15;
    int e  = tl_e[tile];
    int m0 = tl_m[tile];
    int ce = cnt[e];
    int oe = offs[e];
    int n0 = nt * 128;
    int lane = tid & 63, w = tid >> 6;
    int csrc = (lane & 3) ^ ((lane >> 3) & 3);
    const ushort* asrc0; const ushort* asrc1;
    {
      int r = (2*w)*16 + (lane >> 2);
      asrc0 = act + (size_t)(oe + min(m0 + r,      ce - 1)) * FD + csrc * 8;
      asrc1 = act + (size_t)(oe + min(m0 + r + 16, ce - 1)) * FD + csrc * 8;
    }
    const ushort* bsrc = wdt + ((size_t)e * HD + n0 + w*16 + (lane >> 2)) * FD + csrc * 8;
    int lm = lane & 15, lg = lane >> 4;
    int wr = w >> 1, wc = w & 1;
    int asw = (lm >> 1) & 3;

    f32x4 acc[4][4];
    #pragma unroll
    for (int m = 0; m < 4; ++m)
      #pragma unroll
      for (int n = 0; n < 4; ++n) acc[m][n] = f32x4{0,0,0,0};

    #define DNB_ISSUE(T, BUF) do { \
      GLOAD_LDS16(asrc0 + (T)*32, Ap + (BUF)*8192 + (2*w)*512); \
      GLOAD_LDS16(asrc1 + (T)*32, Ap + (BUF)*8192 + (2*w+1)*512); \
      GLOAD_LDS16(bsrc + (T)*32, Bdp + (BUF)*4096 + w*512); \
    } while (0)
    #define DNB_COMPUTE(BUF) do { \
      bf16x8 a[4], bvv[4]; \
      _Pragma("unroll") \
      for (int m = 0; m < 4; ++m) \
        a[m] = *(const bf16x8*)(Ap + (BUF)*8192 + (wr*64 + m*16 + lm)*32 + (lg ^ asw)*8); \
      _Pragma("unroll") \
      for (int n = 0; n < 4; ++n) { \
        int row = wc*64 + n*16 + lm; \
        bvv[n] = *(const bf16x8*)(Bdp + (BUF)*4096 + row*32 + (lg ^ asw)*8); \
      } \
      __builtin_amdgcn_s_setprio(1); \
      _Pragma("unroll") \
      for (int m = 0; m < 4; ++m) \
        _Pragma("unroll") \
        for (int n = 0; n < 4; ++n) \
          acc[m][n] = __builtin_amdgcn_mfma_f32_16x16x32_bf16(a[m], bvv[n], acc[m][n], 0, 0, 0); \
      __builtin_amdgcn_s_setprio(0); \
    } while (0)

    DNB_ISSUE(0, 0);
    DNB_ISSUE(1, 1);
    WAIT_VM3;
    BAR();
    for (int tt = 0; tt < 10; ++tt) {
      int t = tt * 3;
      DNB_ISSUE(t+2, 2); DNB_COMPUTE(0); WAIT_VM3; BAR();
      DNB_ISSUE(t+3, 0); DNB_COMPUTE(1); WAIT_VM3; BAR();
      DNB_ISSUE(t+4, 1); DNB_COMPUTE(2); WAIT_VM3; BAR();
    }
    DNB_COMPUTE(0); WAIT_VM0; BAR();   // t=30
    DNB_COMPUTE(1);                    // t=31
    #undef DNB_ISSUE
    #undef DNB_COMPUTE

    #pragma unroll
    for (int m = 0; m < 4; ++m) {
      #pragma unroll
      for (int j = 0; j < 4; ++j) {
        int rl = wr*64 + m*16 + lg*4 + j;
        int pi = m0 + rl;
        if (pi >= ce) continue;
        size_t base = (size_t)(oe + pi) * HD + n0 + wc*64;
        #pragma unroll
        for (int n = 0; n < 4; ++n)
          pairout[base + n*16 + lm] = f2b(acc[m][n][j]);
      }
    }
  } else {
    // ---------- shared_down: BM=256, K=SDIM, STORES y ----------
    ushort* Ap  = pool;
    ushort* Bdp = pool + 24576;
    int sbid = b - 1280;                     // 0..127
    int wid = (sbid & 7) * 16 + (sbid >> 3);
    int mt = wid & 7;
    int nt = wid >> 3;                        // 0..15
    int m0 = mt * 256;
    int n0 = nt * 128;
    int lane = tid & 63, w = tid >> 6;
    int csrc = (lane & 3) ^ ((lane >> 3) & 3);
    const ushort* asrc0; const ushort* asrc1;
    {
      int r = (2*w)*16 + (lane >> 2);
      asrc0 = sact + (size_t)(m0 + r)      * SDIM + csrc * 8;
      asrc1 = sact + (size_t)(m0 + r + 16) * SDIM + csrc * 8;
    }
    const ushort* bsrc = sdb + (size_t)(n0 + w*16 + (lane >> 2)) * SDIM + csrc * 8;
    int lm = lane & 15, lg = lane >> 4;
    int wr = w >> 1, wc = w & 1;
    int asw = (lm >> 1) & 3;

    f32x4 acc[4][4];
    #pragma unroll
    for (int m = 0; m < 4; ++m)
      #pragma unroll
      for (int n = 0; n < 4; ++n) acc[m][n] = f32x4{0,0,0,0};

    #define SDB_ISSUE(T, BUF) do { \
      GLOAD_LDS16(asrc0 + (T)*32, Ap + (BUF)*8192 + (2*w)*512); \
      GLOAD_LDS16(asrc1 + (T)*32, Ap + (BUF)*8192 + (2*w+1)*512); \
      GLOAD_LDS16(bsrc + (T)*32, Bdp + (BUF)*4096 + w*512); \
    } while (0)
    #define SDB_COMPUTE(BUF) do { \
      bf16x8 a[4], bvv[4]; \
      _Pragma("unroll") \
      for (int m = 0; m < 4; ++m) \
        a[m] = *(const bf16x8*)(Ap + (BUF)*8192 + (wr*64 + m*16 + lm)*32 + (lg ^ asw)*8); \
      _Pragma("unroll") \
      for (int n = 0; n < 4; ++n) { \
        int row = wc*64 + n*16 + lm; \
        bvv[n] = *(const bf16x8*)(Bdp + (BUF)*4096 + row*32 + (lg ^ asw)*8); \
      } \
      __builtin_amdgcn_s_setprio(1); \
      _Pragma("unroll") \
      for (int m = 0; m < 4; ++m) \
        _Pragma("unroll") \
        for (int n = 0; n < 4; ++n) \
          acc[m][n] = __builtin_amdgcn_mfma_f32_16x16x32_bf16(a[m], bvv[n], acc[m][n], 0, 0, 0); \
      __builtin_amdgcn_s_setprio(0); \
    } while (0)

    SDB_ISSUE(0, 0);
    SDB_ISSUE(1, 1);
    WAIT_VM3;
    BAR();
    for (int tt = 0; tt < 20; ++tt) {
      int t = tt * 3;
      SDB_ISSUE(t+2, 2); SDB_COMPUTE(0); WAIT_VM3; BAR();
      SDB_ISSUE(t+3, 0); SDB_COMPUTE(1); WAIT_VM3; BAR();
      SDB_ISSUE(t+4, 1); SDB_COMPUTE(2); WAIT_VM3; BAR();
    }
    SDB_ISSUE(62, 2); SDB_COMPUTE(0); WAIT_VM3; BAR();   // t=60
    SDB_ISSUE(63, 0); SDB_COMPUTE(1); WAIT_VM3; BAR();   // t=61
    SDB_COMPUTE(2); WAIT_VM0; BAR();                     // t=62
    SDB_COMPUTE(0);                                      // t=63
    #undef SDB_ISSUE
    #undef SDB_COMPUTE

    #pragma unroll
    for (int m = 0; m < 4; ++m) {
      #pragma unroll
      for (int j = 0; j < 4; ++j) {
        int rl = wr*64 + m*16 + lg*4 + j;
        size_t base = (size_t)(m0 + rl) * HD + n0 + wc*64;
        #pragma unroll
        for (int n = 0; n < 4; ++n)
          y[base + n*16 + lm] = acc[m][n][j];   // store (combine adds routed)
      }
    }
  }
}

// ---------------- launch ----------------
extern "C" void kernel_launch(void* const* d_in, const int* in_sizes, int n_in,
                              void* d_out, int out_size, void* d_ws, size_t ws_size,
                              hipStream_t stream) {
  const float* x     = (const float*)d_in[0];
  const float* wgate = (const float*)d_in[1];
  const float* wg    = (const float*)d_in[2];
  const float* wu    = (const float*)d_in[3];
  const float* wd    = (const float*)d_in[4];
  const float* sg    = (const float*)d_in[5];
  const float* su    = (const float*)d_in[6];
  const float* sd    = (const float*)d_in[7];
  float* y = (float*)d_out;
  char* ws = (char*)d_ws;

  ushort* xb   = (ushort*)(ws + 0);
  ushort* act  = (ushort*)(ws + 8388608);
  ushort* sact = (ushort*)(ws + 33554432);
  int*    tidx = (int*)  (ws + 41943040);
  float*  tw   = (float*)(ws + 41992192);
  int*    ptok = (int*)  (ws + 42041344);
  float*  pw   = (float*)(ws + 42090496);
  int*    cnt  = (int*)  (ws + 42139648);
  int*    curc = (int*)  (ws + 42139776);
  int*    offs = (int*)  (ws + 42139904);
  int*    tl_e = (int*)  (ws + 42140160);
  int*    tl_m = (int*)  (ws + 42140672);
  int*    ntl  = (int*)  (ws + 42141184);
  int*    inv  = (int*)  (ws + 42141440);
  ushort* wgt  = (ushort*)(ws + 50331648);    // 128 MB [E][F][H]
  ushort* wut  = (ushort*)(ws + 184549376);   // 128 MB
  ushort* wdt  = (ushort*)(ws + 318767104);   // 128 MB [E][H][F]
  ushort* sgb  = (ushort*)(ws + 452984832);   // 8 MB
  ushort* sub  = (ushort*)(ws + 461373440);
  ushort* sdb  = (ushort*)(ws + 469762048);
  // pairout ALIASES wgt: wgt last read in mega_gu; pairout written in mega_dn (later launch)
  ushort* pairout = wgt;

  hipMemsetAsync(cnt, 0, 512, stream);

  gating_kernel<<<dim3(TT), dim3(64), 0, stream>>>(x, wgate, tidx, tw, cnt);
  scan_kernel<<<dim3(1), dim3(64), 0, stream>>>(cnt, offs, tl_e, tl_m, ntl);
  fill_kernel<<<dim3(48), dim3(256), 0, stream>>>(tidx, tw, offs, curc, ptok, pw, inv);

  fconv4<<<dim3(4096, 4), dim3(256), 0, stream>>>(x, sg, su, sd, xb, sgb, sub, sdb);
  tconvA<<<dim3(16384), dim3(512), 0, stream>>>(wg, wu, wgt, wut);

  mega_gu<<<dim3(1280 + 8192 + 256), dim3(512), 0, stream>>>(
      xb, wgt, wut, ptok, pw, cnt, offs, tl_e, tl_m, ntl, act,
      wd, wdt, sgb, sub, sact);
  mega_dn<<<dim3(1280 + 128), dim3(512), 0, stream>>>(
      act, wdt, cnt, offs, tl_e, tl_m, ntl, pairout, sact, sdb, y);
  combine_kernel<<<dim3(TT), dim3(256), 0, stream>>>(pairout, inv, y);
}